// Round 6
// baseline (139.762 us; speedup 1.0000x reference)
//
#include <hip/hip_runtime.h>

#define IC    128
#define OC    128
#define NL    81          // degrees 0..80
#define PTOT  6561        // (L+1)^2 positions
#define NCPT  17
#define BSTR  (IC*PTOT)   // x batch stride
#define NBLK  1568        // 16 b * (64 blocks for l<64 + 2*17 for l>=64)

typedef short short8 __attribute__((ext_vector_type(8)));
typedef float f32x4  __attribute__((ext_vector_type(4)));

__device__ __forceinline__ unsigned short f2bf(float x) {
    unsigned u = __float_as_uint(x);
    return (unsigned short)((u + 0x7FFFu + ((u >> 16) & 1u)) >> 16);
}

// 4 blocks per degree l. Emit W_l in MFMA A-fragment order:
//   elem offset within degree = (of*4+kk)*512 + lane*8 + j
//   where o = of*16 + (lane&15), i = kk*32 + (lane>>4)*8 + j.
__global__ __launch_bounds__(256) void shconv_prep(const float* __restrict__ w,
                                                   unsigned short* __restrict__ WtF) {
    const int l    = blockIdx.x >> 2;
    const int quad = blockIdx.x & 3;
    int s; float fr;
    if (l < 75) { s = l / 5;  fr = (float)(l - s * 5) * 0.2f; }
    else        { s = 15;     fr = (float)(l - 75) * 0.2f;    }
    unsigned short* dst = WtF + (size_t)l * (OC * IC);
    const int e0 = quad * 4096;
    for (int e = e0 + threadIdx.x; e < e0 + 4096; e += 256) {
        int j  = e & 7;
        int mm = (e >> 3) & 15;
        int gg = (e >> 7) & 3;
        int kk = (e >> 9) & 3;
        int of = e >> 11;
        int o = of * 16 + mm;
        int i = kk * 32 + gg * 8 + j;
        const float* wp = w + i * (OC * NCPT) + o * NCPT + s;
        float v = (1.0f - fr) * wp[0] + fr * wp[1];
        dst[e] = f2bf(v);
    }
}

// Block = (b, l, chunk): M=128 (all o), N=128 consecutive p of batch b's
// degree-l segment (p-start rounded down to a multiple of 4; masked stores).
// Wave = M-half (mh) x N-half (nh): 64 o x 64 p, as 4 interleaved 16-col
// MFMA tiles with col m of tile d <-> p = pr + 4m + d. All x reads and out
// writes are p-contiguous dwords -> full cache-line/DRAM-page utilization.
// Tail lanes clamp pr to PTOT-4; loads AND stores both use pr so clamped
// lanes redundantly (but correctly) rewrite the last few positions.
__global__ __launch_bounds__(256, 2) void shconv_main(const float* __restrict__ x,
                                                      const unsigned short* __restrict__ WtF,
                                                      float* __restrict__ out) {
    const int bid = blockIdx.x;
    const int b   = bid / 98;
    const int r   = bid - b * 98;
    int l, chunk;
    if (r < 64) { l = r; chunk = 0; }
    else        { int rr = r - 64; l = 64 + (rr >> 1); chunk = rr & 1; }

    const int p2     = l * l;
    const int len    = 2 * l + 1;
    const int pstart = p2 & ~3;

    const int tid  = threadIdx.x;
    const int wave = tid >> 6;
    const int lane = tid & 63;
    const int m    = lane & 15;
    const int g    = lane >> 4;
    const int nh   = wave & 1;     // N half
    const int mh   = wave >> 1;    // M half

    const int pcol = pstart + chunk * 128 + nh * 64 + 4 * m;
    int pr = pcol; if (pr > PTOT - 4) pr = PTOT - 4;

    const float* xg = x + (size_t)b * BSTR + (size_t)(g * 8) * PTOT + pr;
    // of_global = mh*4 + of  ->  frag offset ((mh*4+of)*4+kk)*512
    const unsigned short* wf = WtF + (size_t)l * (OC * IC) + (size_t)mh * 8192
                                   + (size_t)lane * 8;

    f32x4 acc[4][4];
    #pragma unroll
    for (int of = 0; of < 4; ++of)
        #pragma unroll
        for (int d = 0; d < 4; ++d) acc[of][d] = (f32x4){0.f, 0.f, 0.f, 0.f};

    #pragma unroll
    for (int kk = 0; kk < 4; ++kk) {
        float v[8][4];
        #pragma unroll
        for (int j = 0; j < 8; ++j)
            #pragma unroll
            for (int d = 0; d < 4; ++d)
                v[j][d] = xg[(size_t)(kk * 32 + j) * PTOT + d];

        short8 bfr[4];
        #pragma unroll
        for (int d = 0; d < 4; ++d)
            #pragma unroll
            for (int j = 0; j < 8; ++j)
                bfr[d][j] = (short)f2bf(v[j][d]);

        short8 af[4];
        #pragma unroll
        for (int of = 0; of < 4; ++of)
            af[of] = *(const short8*)(wf + ((size_t)(of * 4 + kk) << 9));

        #pragma unroll
        for (int of = 0; of < 4; ++of)
            #pragma unroll
            for (int d = 0; d < 4; ++d)
                acc[of][d] = __builtin_amdgcn_mfma_f32_16x16x32_bf16(af[of], bfr[d], acc[of][d], 0, 0, 0);
    }

    // stores: per (of, j): 4 dword stores along d (p-contiguous across lanes;
    // L2 merges the d-split into full lines). Mask to [p2, p2+len).
    // NOTE: store index uses pr (same base as the loads) so clamped tail
    // lanes store their data at the positions it was computed from.
    float* ob0 = out + (size_t)b * (OC * PTOT);
    const int phi = p2 + len;
    #pragma unroll
    for (int of = 0; of < 4; ++of) {
        const int obase = (mh * 4 + of) * 16 + g * 4;
        #pragma unroll
        for (int j = 0; j < 4; ++j) {
            float* ob = ob0 + (size_t)(obase + j) * PTOT;
            #pragma unroll
            for (int d = 0; d < 4; ++d) {
                int p = pr + d;
                if (p >= p2 && p < phi) ob[p] = acc[of][d][j];
            }
        }
    }
}

extern "C" void kernel_launch(void* const* d_in, const int* in_sizes, int n_in,
                              void* d_out, int out_size, void* d_ws, size_t ws_size,
                              hipStream_t stream) {
    const float* x = (const float*)d_in[0];
    const float* w = (const float*)d_in[1];
    unsigned short* WtF = (unsigned short*)d_ws;    // 81*128*128 bf16 = 2.65 MB
    float* out = (float*)d_out;

    shconv_prep<<<dim3(NL * 4), dim3(256), 0, stream>>>(w, WtF);
    shconv_main<<<dim3(NBLK),   dim3(256), 0, stream>>>(x, WtF, out);
}

// Round 7
// 127.003 us; speedup vs baseline: 1.1005x; 1.1005x over previous
//
#include <hip/hip_runtime.h>
#include <stdint.h>

#define IC    128
#define OC    128
#define NL    81
#define PTOT  6561
#define NCPT  17
#define BSTR  (IC*PTOT)
#define XN    (16*BSTR)      // total floats in x
#define NPB   147            // blocks per batch: 32 + 32*2 + 17*3
#define NBLK  (16*NPB)

#define ROWF  72             // floats per LDS row: 64-p window + phase(<=3) + slack
#define ROWB  (ROWF*4)       // 288 B; 128 rows = 36864 B LDS

typedef short short8 __attribute__((ext_vector_type(8)));
typedef float f32x4  __attribute__((ext_vector_type(4)));

#define AS1 __attribute__((address_space(1)))
#define AS3 __attribute__((address_space(3)))

__device__ __forceinline__ unsigned short f2bf(float x) {
    unsigned u = __float_as_uint(x);
    return (unsigned short)((u + 0x7FFFu + ((u >> 16) & 1u)) >> 16);
}

// 4 blocks per degree l. Emit W_l in MFMA A-fragment order:
//   elem offset within degree = (of*4+kk)*512 + lane*8 + j
//   where o = of*16 + (lane&15), i = kk*32 + (lane>>4)*8 + j.
__global__ __launch_bounds__(256) void shconv_prep(const float* __restrict__ w,
                                                   unsigned short* __restrict__ WtF) {
    const int l    = blockIdx.x >> 2;
    const int quad = blockIdx.x & 3;
    int s; float fr;
    if (l < 75) { s = l / 5;  fr = (float)(l - s * 5) * 0.2f; }
    else        { s = 15;     fr = (float)(l - 75) * 0.2f;    }
    unsigned short* dst = WtF + (size_t)l * (OC * IC);
    const int e0 = quad * 4096;
    for (int e = e0 + threadIdx.x; e < e0 + 4096; e += 256) {
        int j  = e & 7;
        int mm = (e >> 3) & 15;
        int gg = (e >> 7) & 3;
        int kk = (e >> 9) & 3;
        int of = e >> 11;
        int o = of * 16 + mm;
        int i = kk * 32 + gg * 8 + j;
        const float* wp = w + i * (OC * NCPT) + o * NCPT + s;
        float v = (1.0f - fr) * wp[0] + fr * wp[1];
        dst[e] = f2bf(v);
    }
}

// Block = (b, l, 64-p window). Stage 128ch x 64p of x (f32) into LDS with
// global_load_lds dwordx4 (async, per-lane src, 16B-aligned via per-row
// floor + phase s). Row r holds channel ch = ((r&15)<<3)|(r>>4) so that the
// B-frag's 4 g-groups read distinct LDS banks. One barrier, then MFMA.
__global__ __launch_bounds__(256, 4) void shconv_main(const float* __restrict__ x,
                                                      const unsigned short* __restrict__ WtF,
                                                      float* __restrict__ out) {
    __shared__ float sx[128 * ROWF];

    const int bid = blockIdx.x;
    const int b   = bid / NPB;
    const int r0  = bid - b * NPB;
    int l, chunk;
    if (r0 < 32)      { l = r0;               chunk = 0; }
    else if (r0 < 96) { int rr = r0 - 32; l = 32 + (rr >> 1); chunk = rr & 1; }
    else              { int rr = r0 - 96; int q3 = rr / 3; l = 64 + q3; chunk = rr - q3 * 3; }

    const int plen = 2 * l + 1;
    const int pw   = l * l + chunk * 64;
    int lenw = plen - chunk * 64; if (lenw > 64) lenw = 64;

    const int tid  = threadIdx.x;
    const int wq   = tid >> 6;
    const int lane = tid & 63;

    // ---- async stage: 9 x 1KB per wave, LDS linear, per-lane global src ----
    #pragma unroll
    for (int i = 0; i < 9; ++i) {
        const int ldsoff = wq * 9216 + i * 1024;        // wave-uniform base
        int off = ldsoff + lane * 16;                   // this lane's dest
        int r   = (unsigned)off / ROWB;
        int c   = off - r * ROWB;
        int ch  = ((r & 15) << 3) | (r >> 4);
        int R   = ch * PTOT + pw;
        int A4  = R & ~3;
        int s   = R - A4;
        int needC = (4 * (s + lenw) - 1) & ~15;         // last needed 16B chunk
        int ce  = c < needC ? c : needC;                // dedupe overhang -> L1 hit
        long fidx = (long)b * BSTR + A4 + (ce >> 2);
        if (fidx > (long)XN - 4) fidx = (long)XN - 4;   // array-end guard
        __builtin_amdgcn_global_load_lds((const AS1 uint32_t*)(x + fidx),
                                         (AS3 uint32_t*)(sx + (ldsoff >> 2)),
                                         16, 0, 0);
    }
    asm volatile("s_waitcnt vmcnt(0)" ::: "memory");
    __syncthreads();

    const int m  = lane & 15;
    const int g  = lane >> 4;
    const int mh = wq >> 1;      // o-half (64 rows)
    const int nh = wq & 1;       // p-half (32 cols)

    const unsigned short* wfb = WtF + (size_t)l * (OC * IC) + (size_t)mh * 8192
                                    + (size_t)lane * 8;

    f32x4 acc[4][2];
    #pragma unroll
    for (int of = 0; of < 4; ++of)
        #pragma unroll
        for (int pt = 0; pt < 2; ++pt) acc[of][pt] = (f32x4){0.f, 0.f, 0.f, 0.f};

    #pragma unroll
    for (int kk = 0; kk < 4; ++kk) {
        short8 wfr[4];
        #pragma unroll
        for (int of = 0; of < 4; ++of)
            wfr[of] = *(const short8*)(wfb + ((size_t)(of * 4 + kk) << 9));

        #pragma unroll
        for (int pt = 0; pt < 2; ++pt) {
            const int pl = nh * 32 + pt * 16 + m;
            short8 bfr;
            #pragma unroll
            for (int j = 0; j < 8; ++j) {
                int ch  = kk * 32 + g * 8 + j;
                int row = ((ch & 7) << 4) | (ch >> 3);
                int sc  = (ch + pw) & 3;
                bfr[j] = (short)f2bf(sx[row * ROWF + sc + pl]);
            }
            #pragma unroll
            for (int of = 0; of < 4; ++of)
                acc[of][pt] = __builtin_amdgcn_mfma_f32_16x16x32_bf16(wfr[of], bfr, acc[of][pt], 0, 0, 0);
        }
    }

    // masked dword stores (64B segments along p; merged fine per round-6 data)
    float* ob0 = out + (size_t)b * (OC * PTOT);
    #pragma unroll
    for (int of = 0; of < 4; ++of) {
        #pragma unroll
        for (int pt = 0; pt < 2; ++pt) {
            const int pl = nh * 32 + pt * 16 + m;
            const int pd = chunk * 64 + pl;
            if (pd < plen) {
                const int p = l * l + pd;
                #pragma unroll
                for (int j = 0; j < 4; ++j)
                    ob0[(size_t)(mh * 64 + of * 16 + g * 4 + j) * PTOT + p] = acc[of][pt][j];
            }
        }
    }
}

extern "C" void kernel_launch(void* const* d_in, const int* in_sizes, int n_in,
                              void* d_out, int out_size, void* d_ws, size_t ws_size,
                              hipStream_t stream) {
    const float* x = (const float*)d_in[0];
    const float* w = (const float*)d_in[1];
    unsigned short* WtF = (unsigned short*)d_ws;    // 81*128*128 bf16 = 2.65 MB
    float* out = (float*)d_out;

    shconv_prep<<<dim3(NL * 4), dim3(256), 0, stream>>>(w, WtF);
    shconv_main<<<dim3(NBLK),   dim3(256), 0, stream>>>(x, WtF, out);
}

// Round 12
// 126.209 us; speedup vs baseline: 1.1074x; 1.0063x over previous
//
#include <hip/hip_runtime.h>
#include <stdint.h>

#define IC    128
#define OC    128
#define NL    81
#define PTOT  6561
#define NCPT  17
#define BSTR  (IC*PTOT)
#define XN    (16*BSTR)
#define NLC   147            // (l,chunk) windows per batch
#define NBLK  1176           // NLC*16/2  (each block: 2 batches of one window)

#define ROWF  72             // floats per LDS row
#define ROWB  (ROWF*4)       // 288 B
#define BUFF  (128*ROWF)     // floats per buffer (36864 B)

typedef short short8 __attribute__((ext_vector_type(8)));
typedef float f32x4  __attribute__((ext_vector_type(4)));

#define AS1 __attribute__((address_space(1)))
#define AS3 __attribute__((address_space(3)))

__device__ __forceinline__ unsigned short f2bf(float x) {
    unsigned u = __float_as_uint(x);
    return (unsigned short)((u + 0x7FFFu + ((u >> 16) & 1u)) >> 16);
}

__global__ __launch_bounds__(256) void shconv_prep(const float* __restrict__ w,
                                                   unsigned short* __restrict__ WtF) {
    const int l    = blockIdx.x >> 2;
    const int quad = blockIdx.x & 3;
    int s; float fr;
    if (l < 75) { s = l / 5;  fr = (float)(l - s * 5) * 0.2f; }
    else        { s = 15;     fr = (float)(l - 75) * 0.2f;    }
    unsigned short* dst = WtF + (size_t)l * (OC * IC);
    const int e0 = quad * 4096;
    for (int e = e0 + threadIdx.x; e < e0 + 4096; e += 256) {
        int j  = e & 7;
        int mm = (e >> 3) & 15;
        int gg = (e >> 7) & 3;
        int kk = (e >> 9) & 3;
        int of = e >> 11;
        int o = of * 16 + mm;
        int i = kk * 32 + gg * 8 + j;
        const float* wp = w + i * (OC * NCPT) + o * NCPT + s;
        float v = (1.0f - fr) * wp[0] + fr * wp[1];
        dst[e] = f2bf(v);
    }
}

// Block k: window (l,chunk)=lc(k>>3), batches b0=(k&7)*2 and b0+1, LDS
// double-buffered. Counted-wait pipeline: STAGE(1) overlaps MFMA(0); the
// mid vmcnt(0) waits ONLY buf1's 9 loads (stores issued after the barrier),
// so loads stay in flight through compute+store phases.
__global__ __launch_bounds__(256, 2) void shconv_main(const float* __restrict__ x,
                                                      const unsigned short* __restrict__ WtF,
                                                      float* __restrict__ out) {
    __shared__ float sx[2 * BUFF];

    const int k  = blockIdx.x;
    const int lc = k >> 3;
    const int b0 = (k & 7) << 1;
    int l, chunk;
    if (lc < 32)      { l = lc;                    chunk = 0; }
    else if (lc < 96) { int rr = lc - 32; l = 32 + (rr >> 1); chunk = rr & 1; }
    else              { int rr = lc - 96; int q3 = rr / 3; l = 64 + q3; chunk = rr - q3 * 3; }

    const int plen = 2 * l + 1;
    const int pw   = l * l + chunk * 64;
    int lenw = plen - chunk * 64; if (lenw > 64) lenw = 64;

    const int tid  = threadIdx.x;
    const int wq   = tid >> 6;
    const int lane = tid & 63;
    const int m    = lane & 15;
    const int g    = lane >> 4;
    const int mh   = wq >> 1;
    const int nh   = wq & 1;

    // ---- A-frags once per block (same l for both windows): 16 b128 loads ----
    const unsigned short* wfb = WtF + (size_t)l * (OC * IC) + (size_t)mh * 8192
                                    + (size_t)lane * 8;
    short8 wfr[16];
    #pragma unroll
    for (int f = 0; f < 16; ++f)
        wfr[f] = *(const short8*)(wfb + ((size_t)f << 9));
    __builtin_amdgcn_sched_barrier(0);

#define STAGE(BUF, BB)                                                          \
    {                                                                           \
        _Pragma("unroll")                                                       \
        for (int i = 0; i < 9; ++i) {                                           \
            const int ldsoff = wq * 9216 + i * 1024;                            \
            int off = ldsoff + lane * 16;                                       \
            int r   = (unsigned)off / ROWB;                                     \
            int c   = off - r * ROWB;                                           \
            int ch  = ((r & 15) << 3) | (r >> 4);                               \
            int R   = ch * PTOT + pw;                                           \
            int A4  = R & ~3;                                                   \
            int s   = R - A4;                                                   \
            int needC = (4 * (s + lenw) - 1) & ~15;                             \
            int ce  = c < needC ? c : needC;                                    \
            long fidx = (long)(BB) * BSTR + A4 + (ce >> 2);                     \
            if (fidx > (long)XN - 4) fidx = (long)XN - 4;                       \
            __builtin_amdgcn_global_load_lds((const AS1 uint32_t*)(x + fidx),   \
                (AS3 uint32_t*)(sx + (BUF) * BUFF + (ldsoff >> 2)), 16, 0, 0);  \
        }                                                                       \
    }

#define MFMA_PHASE(BUF, ACC)                                                    \
    {                                                                           \
        _Pragma("unroll")                                                       \
        for (int kk = 0; kk < 4; ++kk) {                                        \
            _Pragma("unroll")                                                   \
            for (int pt = 0; pt < 2; ++pt) {                                    \
                const int pl = nh * 32 + pt * 16 + m;                           \
                short8 bfr;                                                     \
                _Pragma("unroll")                                               \
                for (int j = 0; j < 8; ++j) {                                   \
                    int ch  = kk * 32 + g * 8 + j;                              \
                    int row = ((ch & 7) << 4) | (ch >> 3);                      \
                    int sc  = (ch + pw) & 3;                                    \
                    bfr[j] = (short)f2bf(sx[(BUF) * BUFF + row * ROWF + sc + pl]); \
                }                                                               \
                _Pragma("unroll")                                               \
                for (int of = 0; of < 4; ++of)                                  \
                    ACC[of][pt] = __builtin_amdgcn_mfma_f32_16x16x32_bf16(      \
                        wfr[of * 4 + kk], bfr, ACC[of][pt], 0, 0, 0);           \
            }                                                                   \
        }                                                                       \
    }

#define STORES(ACC, BB)                                                         \
    {                                                                           \
        float* ob0 = out + (size_t)(BB) * (OC * PTOT);                          \
        _Pragma("unroll")                                                       \
        for (int of = 0; of < 4; ++of) {                                        \
            _Pragma("unroll")                                                   \
            for (int pt = 0; pt < 2; ++pt) {                                    \
                const int pl = nh * 32 + pt * 16 + m;                           \
                const int pd = chunk * 64 + pl;                                 \
                if (pd < plen) {                                                \
                    const int p = l * l + pd;                                   \
                    _Pragma("unroll")                                           \
                    for (int j = 0; j < 4; ++j)                                 \
                        ob0[(size_t)(mh * 64 + of * 16 + g * 4 + j) * PTOT + p] \
                            = ACC[of][pt][j];                                   \
                }                                                               \
            }                                                                   \
        }                                                                       \
    }

    // ---- prologue: window 0 staged, everything retired once ----
    STAGE(0, b0)
    asm volatile("s_waitcnt vmcnt(0)" ::: "memory");
    __builtin_amdgcn_sched_barrier(0);
    __builtin_amdgcn_s_barrier();

    // ---- phase 0: prefetch window 1, compute window 0 ----
    STAGE(1, b0 + 1)
    f32x4 acc0[4][2];
    #pragma unroll
    for (int of = 0; of < 4; ++of)
        #pragma unroll
        for (int pt = 0; pt < 2; ++pt) acc0[of][pt] = (f32x4){0.f, 0.f, 0.f, 0.f};
    MFMA_PHASE(0, acc0)

    // only buf1's 9 loads are outstanding here (A-frags retired in prologue,
    // stores not yet issued) -> this waits exactly L1, no drain.
    asm volatile("s_waitcnt vmcnt(0)" ::: "memory");
    __builtin_amdgcn_sched_barrier(0);
    __builtin_amdgcn_s_barrier();

    // ---- stores of window 0 overlap compute of window 1 ----
    STORES(acc0, b0)

    f32x4 acc1[4][2];
    #pragma unroll
    for (int of = 0; of < 4; ++of)
        #pragma unroll
        for (int pt = 0; pt < 2; ++pt) acc1[of][pt] = (f32x4){0.f, 0.f, 0.f, 0.f};
    MFMA_PHASE(1, acc1)
    STORES(acc1, b0 + 1)

#undef STAGE
#undef MFMA_PHASE
#undef STORES
}

extern "C" void kernel_launch(void* const* d_in, const int* in_sizes, int n_in,
                              void* d_out, int out_size, void* d_ws, size_t ws_size,
                              hipStream_t stream) {
    const float* x = (const float*)d_in[0];
    const float* w = (const float*)d_in[1];
    unsigned short* WtF = (unsigned short*)d_ws;    // 81*128*128 bf16 = 2.65 MB
    float* out = (float*)d_out;

    shconv_prep<<<dim3(NL * 4), dim3(256), 0, stream>>>(w, WtF);
    shconv_main<<<dim3(NBLK),   dim3(256), 0, stream>>>(x, WtF, out);
}